// Round 9
// baseline (144.292 us; speedup 1.0000x reference)
//
#include <hip/hip_runtime.h>
#include <math.h>

constexpr int S = 2048, D = 64;
constexpr int BH = 64;
constexpr int QTILE = 256;      // 8 waves x 32 q rows
constexpr int KVB = 64;
constexpr int NQT = S / QTILE;  // 8
constexpr float QSCALE = 0.18033688011112042f;  // log2(e)/8
constexpr float DMTHR = 5.0f;   // defer-max threshold (exp2 domain)

typedef float f32x4 __attribute__((ext_vector_type(4)));
typedef float f32x16 __attribute__((ext_vector_type(16)));
typedef _Float16 f16x8 __attribute__((ext_vector_type(8)));
typedef _Float16 f16x4 __attribute__((ext_vector_type(4)));
typedef unsigned int u32;
typedef unsigned int u32x4 __attribute__((ext_vector_type(4)));

#define MFMA32(a, b, c) __builtin_amdgcn_mfma_f32_32x32x16_f16((a), (b), (c), 0, 0, 0)

#if __has_builtin(__builtin_amdgcn_exp2f)
#define EXP2(x) __builtin_amdgcn_exp2f(x)
#else
#define EXP2(x) exp2f(x)
#endif

#define MAX3(a, b, c) fmaxf(fmaxf((a), (b)), (c))  // fuses to v_max3_f32

__device__ __forceinline__ u32 pkbits(float a, float b) {
  return __builtin_bit_cast(u32, __builtin_amdgcn_cvt_pkrtz(a, b));
}
// exchanges a.lanes[32:63] with b.lanes[0:31]; a,b must be distinct values
__device__ __forceinline__ void plswap(u32& a, u32& b) {
  asm volatile("v_permlane32_swap_b32 %0, %1" : "+v"(a), "+v"(b));
}
// XOR swizzle (units of 8 halves): bank period 64 rows
__device__ __forceinline__ int swzb(int row) { return ((row & 7) ^ (row >> 3)) << 3; }

// ---- per-tile compute, forced inline (R8's non-inlined lambda caused scratch spills)
__device__ __forceinline__ void compute_tile(
    const int kt, const int Rp, const int q32, const int hi,
    const _Float16* __restrict__ Kb, const _Float16* __restrict__ Vb,
    const f16x8 (&bq)[4], f32x16& od0, f32x16& od1, float& m, float& l) {
  const int ck = kt * KVB;
  if (ck > Rp + 31) return;         // wave fully masked
  const int rel = Rp - ck;          // >= 0, multiple of 32
  const int ctmax = (rel >= 32) ? 1 : 0;
  const bool needmask = (32 * ctmax + 31 > rel);

  // ---- S^T = mfma(K, Q): lane owns q=Rp+q32, k = 32ct + 8*(r>>2)+4hi+(r&3)
  f32x16 st0 = {}, st1 = {};
  __builtin_amdgcn_s_setprio(1);
#pragma unroll
  for (int t = 0; t < 4; ++t) {
    f16x8 a = *(const f16x8*)&Kb[(q32 << 6) + (swzb(q32) ^ (16 * t + 8 * hi))];
    st0 = MFMA32(a, bq[t], st0);
  }
  if (ctmax) {
    const int row = 32 + q32;
#pragma unroll
    for (int t = 0; t < 4; ++t) {
      f16x8 a = *(const f16x8*)&Kb[(row << 6) + (swzb(row) ^ (16 * t + 8 * hi))];
      st1 = MFMA32(a, bq[t], st1);
    }
  }
  __builtin_amdgcn_s_setprio(0);

  if (needmask) {  // one diagonal tile per wave over whole kernel
    const int qrel = rel + q32;
#pragma unroll
    for (int gq = 0; gq < 4; ++gq)
#pragma unroll
      for (int i = 0; i < 4; ++i) {
        if (8 * gq + 4 * hi + i > qrel) st0[4 * gq + i] = -INFINITY;
        if (ctmax && (32 + 8 * gq + 4 * hi + i > qrel)) st1[4 * gq + i] = -INFINITY;
      }
  }

  // ---- row max: v_max3 tree (depth ~4) + cross-half shuffle
  float pmax;
  {
    const float a0 = MAX3(st0[0], st0[1], st0[2]);
    const float a1 = MAX3(st0[3], st0[4], st0[5]);
    const float a2 = MAX3(st0[6], st0[7], st0[8]);
    const float a3 = MAX3(st0[9], st0[10], st0[11]);
    const float a4 = MAX3(st0[12], st0[13], st0[14]);
    const float b0 = MAX3(a0, a1, st0[15]);
    const float b1 = fmaxf(a2, a3);
    pmax = MAX3(b0, b1, a4);
  }
  if (ctmax) {
    const float a0 = MAX3(st1[0], st1[1], st1[2]);
    const float a1 = MAX3(st1[3], st1[4], st1[5]);
    const float a2 = MAX3(st1[6], st1[7], st1[8]);
    const float a3 = MAX3(st1[9], st1[10], st1[11]);
    const float a4 = MAX3(st1[12], st1[13], st1[14]);
    const float b0 = MAX3(a0, a1, st1[15]);
    const float b1 = MAX3(a2, a3, pmax);
    pmax = MAX3(b0, b1, a4);
  }
  pmax = fmaxf(pmax, __shfl_xor(pmax, 32));

  // ---- defer-max (T13): rescale is pure per-lane
  if (!__all(pmax - m <= DMTHR)) {
    const float mn = fmaxf(m, pmax);
    const float alpha = EXP2(m - mn);
    m = mn;
    l *= alpha;
#pragma unroll
    for (int r = 0; r < 16; ++r) od0[r] *= alpha;
#pragma unroll
    for (int r = 0; r < 16; ++r) od1[r] *= alpha;
  }

  // ---- P = exp2(S - m); in-lane partial sum
  float ps = 0.f;
#pragma unroll
  for (int r = 0; r < 16; ++r) { const float p = EXP2(st0[r] - m); st0[r] = p; ps += p; }
  if (ctmax)
#pragma unroll
    for (int r = 0; r < 16; ++r) { const float p = EXP2(st1[r] - m); st1[r] = p; ps += p; }
  l += ps;

  // ---- P -> B-frag via cvt_pk + permlane32_swap (T12); O^T += mfma(V^T, P^T)
  __builtin_amdgcn_s_setprio(1);
#define PV_CT(stv, CT)                                                          \
  _Pragma("unroll")                                                             \
  for (int t = 0; t < 2; ++t) {                                                 \
    u32 x0 = pkbits(stv[8 * t + 0], stv[8 * t + 1]);                            \
    u32 x1 = pkbits(stv[8 * t + 2], stv[8 * t + 3]);                            \
    u32 y0 = pkbits(stv[8 * t + 4], stv[8 * t + 5]);                            \
    u32 y1 = pkbits(stv[8 * t + 6], stv[8 * t + 7]);                            \
    plswap(x0, y0); plswap(x1, y1);                                             \
    const f16x8 pf = __builtin_bit_cast(f16x8, (u32x4){x0, x1, y0, y1});        \
    const int kcol = (2 * (CT) + t) * 16 + 8 * hi;                              \
    { const f16x8 vf = *(const f16x8*)&Vb[(q32 << 6) + (swzb(q32) ^ kcol)];     \
      od0 = MFMA32(vf, pf, od0); }                                              \
    { const int row = 32 + q32;                                                 \
      const f16x8 vf = *(const f16x8*)&Vb[(row << 6) + (swzb(row) ^ kcol)];     \
      od1 = MFMA32(vf, pf, od1); }                                              \
  }
  PV_CT(st0, 0);
  if (ctmax) { PV_CT(st1, 1); }
#undef PV_CT
  __builtin_amdgcn_s_setprio(0);
}

// 32x32x16 swapped flash attn. A-frag: row=l&31, k=(l>>5)*8+j. B-frag: col=l&31 (q).
// C/D: col=l&31 (q), row=(reg&3)+8*(reg>>2)+4*(l>>5)  [m74/m101]
// Two 64-k tiles per barrier (4 LDS buffers); everything force-inlined.
__global__ __launch_bounds__(512, 4)
void attn_fwd(const float* __restrict__ qp, const float* __restrict__ kp,
              const float* __restrict__ vp, float* __restrict__ op) {
  __shared__ _Float16 Kl[4][KVB * 64];  // Kl[buf][k][d], swizzled rows
  __shared__ _Float16 Vt[4][64 * KVB];  // Vt[buf][d][k], swizzled rows

  const int bh = blockIdx.x;
  constexpr int g8[8] = {7, 6, 5, 4, 0, 1, 2, 3};  // CU pairs (y, y+4) sum 7
  const int qt = g8[blockIdx.y];

  const int tid = threadIdx.x;
  const int wid = tid >> 6;
  const int lane = tid & 63;
  const int q32 = lane & 31;
  const int hi = lane >> 5;

  const size_t base = (size_t)bh * (S * D);
  const int Rp = qt * QTILE + wid * 32;  // wave's first q row

  // ---- Q B-frags: bq[t][j] = Q[Rp+q32][16t + 8hi + j] * QSCALE
  f16x8 bq[4];
  {
    const float* qg = qp + base + (size_t)(Rp + q32) * D + 8 * hi;
#pragma unroll
    for (int t = 0; t < 4; ++t) {
      f32x4 a = *(const f32x4*)(qg + 16 * t);
      f32x4 b = *(const f32x4*)(qg + 16 * t + 4);
#pragma unroll
      for (int j = 0; j < 4; ++j) bq[t][j] = (_Float16)(a[j] * QSCALE);
#pragma unroll
      for (int j = 0; j < 4; ++j) bq[t][4 + j] = (_Float16)(b[j] * QSCALE);
    }
  }

  f32x16 od0 = {}, od1 = {};      // O^T: d = 32*dt + 8*(r>>2) + 4*hi + (r&3), q = q32
  float m = -INFINITY, l = 0.f;   // per-lane, own q row

  const int NT = 4 * qt + 4;      // tiles (always even)

  // ---- staging geometry: row-pair rp, 4-col group cg (per 64x64 tile)
  const int rp = tid >> 4;        // 0..31
  const int cg = tid & 15;
  const int r0 = 2 * rp, r1 = 2 * rp + 1;
  const int c4 = cg * 4;
  const int kw0 = (r0 << 6) + (swzb(r0) ^ c4);
  const int kw1 = (r1 << 6) + (swzb(r1) ^ c4);
  const int vw0 = ((c4 + 0) << 6) + (swzb(c4 + 0) ^ r0);
  const int vw1 = ((c4 + 1) << 6) + (swzb(c4 + 1) ^ r0);
  const int vw2 = ((c4 + 2) << 6) + (swzb(c4 + 2) ^ r0);
  const int vw3 = ((c4 + 3) << 6) + (swzb(c4 + 3) ^ r0);

#define LOADT(kt, K0, K1, V0, V1)                                        \
  do {                                                                   \
    const float* kg_ = kp + base + (size_t)((kt) * KVB + r0) * D + c4;   \
    const float* vg_ = vp + base + (size_t)((kt) * KVB + r0) * D + c4;   \
    K0 = *(const f32x4*)kg_; K1 = *(const f32x4*)(kg_ + D);              \
    V0 = *(const f32x4*)vg_; V1 = *(const f32x4*)(vg_ + D);              \
  } while (0)

#define WRITET(buf, K0, K1, V0, V1)                                      \
  do {                                                                   \
    f16x4 k0h_, k1h_;                                                    \
    _Pragma("unroll")                                                    \
    for (int j = 0; j < 4; ++j) {                                        \
      k0h_[j] = (_Float16)K0[j]; k1h_[j] = (_Float16)K1[j];              \
    }                                                                    \
    *(f16x4*)&Kl[buf][kw0] = k0h_;                                       \
    *(f16x4*)&Kl[buf][kw1] = k1h_;                                       \
    *(u32*)&Vt[buf][vw0] = pkbits(V0[0], V1[0]);                         \
    *(u32*)&Vt[buf][vw1] = pkbits(V0[1], V1[1]);                         \
    *(u32*)&Vt[buf][vw2] = pkbits(V0[2], V1[2]);                         \
    *(u32*)&Vt[buf][vw3] = pkbits(V0[3], V1[3]);                         \
  } while (0)

  // ---- main loop: two tiles per barrier
  f32x4 ka0, ka1, va0, va1, kb0, kb1, vb0, vb1;
  LOADT(0, ka0, ka1, va0, va1);
  LOADT(1, kb0, kb1, vb0, vb1);

  for (int ktp = 0; ktp < NT; ktp += 2) {
    const int b0 = ktp & 2;  // buffer pair alternates {0,1} / {2,3}
    WRITET(b0, ka0, ka1, va0, va1);
    WRITET(b0 + 1, kb0, kb1, vb0, vb1);
    if (ktp + 2 < NT) LOADT(ktp + 2, ka0, ka1, va0, va1);  // >1 compute phase of cover
    __syncthreads();  // pair ready; prior pair's reads are barrier-ordered
    compute_tile(ktp, Rp, q32, hi, Kl[b0], Vt[b0], bq, od0, od1, m, l);
    if (ktp + 3 < NT) LOADT(ktp + 3, kb0, kb1, vb0, vb1);  // lands under next compute
    compute_tile(ktp + 1, Rp, q32, hi, Kl[b0 + 1], Vt[b0 + 1], bq, od0, od1, m, l);
  }
#undef LOADT
#undef WRITET

  // ---- epilogue: l across partner, scale, b128 stores
  const float lt = l + __shfl_xor(l, 32);
  const float inv = 1.f / lt;
  float* og = op + base + (size_t)(Rp + q32) * D + 4 * hi;
#pragma unroll
  for (int gq = 0; gq < 4; ++gq) {
    f32x4 w0, w1;
#pragma unroll
    for (int i = 0; i < 4; ++i) w0[i] = od0[4 * gq + i] * inv;
#pragma unroll
    for (int i = 0; i < 4; ++i) w1[i] = od1[4 * gq + i] * inv;
    *(f32x4*)(og + 8 * gq) = w0;
    *(f32x4*)(og + 32 + 8 * gq) = w1;
  }
}

extern "C" void kernel_launch(void* const* d_in, const int* in_sizes, int n_in,
                              void* d_out, int out_size, void* d_ws, size_t ws_size,
                              hipStream_t stream) {
  const float* q = (const float*)d_in[0];
  const float* k = (const float*)d_in[1];
  const float* v = (const float*)d_in[2];
  float* out = (float*)d_out;
  dim3 grid(BH, NQT);
  attn_fwd<<<grid, 512, 0, stream>>>(q, k, v, out);
}

// Round 10
// 143.445 us; speedup vs baseline: 1.0059x; 1.0059x over previous
//
#include <hip/hip_runtime.h>
#include <math.h>

constexpr int S = 2048, D = 64;
constexpr int BH = 64;
constexpr int QTILE = 256;      // 8 waves x 32 q rows
constexpr int KVB = 64;
constexpr int NQT = S / QTILE;  // 8
constexpr float QSCALE = 0.18033688011112042f;  // log2(e)/8
constexpr float DMTHR = 5.0f;   // defer-max threshold (exp2 domain)

typedef float f32x4 __attribute__((ext_vector_type(4)));
typedef float f32x16 __attribute__((ext_vector_type(16)));
typedef _Float16 f16x8 __attribute__((ext_vector_type(8)));
typedef _Float16 f16x4 __attribute__((ext_vector_type(4)));
typedef unsigned int u32;
typedef unsigned int u32x4 __attribute__((ext_vector_type(4)));

#define MFMA32(a, b, c) __builtin_amdgcn_mfma_f32_32x32x16_f16((a), (b), (c), 0, 0, 0)

#if __has_builtin(__builtin_amdgcn_exp2f)
#define EXP2(x) __builtin_amdgcn_exp2f(x)
#else
#define EXP2(x) exp2f(x)
#endif

#define MAX3(a, b, c) fmaxf(fmaxf((a), (b)), (c))  // fuses to v_max3_f32

__device__ __forceinline__ u32 pkbits(float a, float b) {
  return __builtin_bit_cast(u32, __builtin_amdgcn_cvt_pkrtz(a, b));
}
// exchanges a.lanes[32:63] with b.lanes[0:31]; a,b must be distinct values
__device__ __forceinline__ void plswap(u32& a, u32& b) {
  asm volatile("v_permlane32_swap_b32 %0, %1" : "+v"(a), "+v"(b));
}
// XOR swizzle (units of 8 halves): bank period 64 rows
__device__ __forceinline__ int swzb(int row) { return ((row & 7) ^ (row >> 3)) << 3; }

// ---- per-tile compute, forced inline
__device__ __forceinline__ void compute_tile(
    const int kt, const int Rp, const int q32, const int hi,
    const _Float16* __restrict__ Kb, const _Float16* __restrict__ Vb,
    const f16x8 (&bq)[4], f32x16& od0, f32x16& od1, float& m, float& l) {
  const int ck = kt * KVB;
  if (ck > Rp + 31) return;         // wave fully masked
  const int rel = Rp - ck;          // >= 0, multiple of 32
  const int ctmax = (rel >= 32) ? 1 : 0;
  const bool needmask = (32 * ctmax + 31 > rel);

  // ---- S^T = mfma(K, Q): lane owns q=Rp+q32, k = 32ct + 8*(r>>2)+4hi+(r&3)
  f32x16 st0 = {}, st1 = {};
  __builtin_amdgcn_s_setprio(1);
#pragma unroll
  for (int t = 0; t < 4; ++t) {
    f16x8 a = *(const f16x8*)&Kb[(q32 << 6) + (swzb(q32) ^ (16 * t + 8 * hi))];
    st0 = MFMA32(a, bq[t], st0);
  }
  if (ctmax) {
    const int row = 32 + q32;
#pragma unroll
    for (int t = 0; t < 4; ++t) {
      f16x8 a = *(const f16x8*)&Kb[(row << 6) + (swzb(row) ^ (16 * t + 8 * hi))];
      st1 = MFMA32(a, bq[t], st1);
    }
  }
  __builtin_amdgcn_s_setprio(0);

  if (needmask) {  // one diagonal tile per wave over whole kernel
    const int qrel = rel + q32;
#pragma unroll
    for (int gq = 0; gq < 4; ++gq)
#pragma unroll
      for (int i = 0; i < 4; ++i) {
        if (8 * gq + 4 * hi + i > qrel) st0[4 * gq + i] = -INFINITY;
        if (ctmax && (32 + 8 * gq + 4 * hi + i > qrel)) st1[4 * gq + i] = -INFINITY;
      }
  }

  // ---- row max: v_max3 tree (depth ~4) + cross-half shuffle
  float pmax;
  {
    const float a0 = MAX3(st0[0], st0[1], st0[2]);
    const float a1 = MAX3(st0[3], st0[4], st0[5]);
    const float a2 = MAX3(st0[6], st0[7], st0[8]);
    const float a3 = MAX3(st0[9], st0[10], st0[11]);
    const float a4 = MAX3(st0[12], st0[13], st0[14]);
    const float b0 = MAX3(a0, a1, st0[15]);
    const float b1 = fmaxf(a2, a3);
    pmax = MAX3(b0, b1, a4);
  }
  if (ctmax) {
    const float a0 = MAX3(st1[0], st1[1], st1[2]);
    const float a1 = MAX3(st1[3], st1[4], st1[5]);
    const float a2 = MAX3(st1[6], st1[7], st1[8]);
    const float a3 = MAX3(st1[9], st1[10], st1[11]);
    const float a4 = MAX3(st1[12], st1[13], st1[14]);
    const float b0 = MAX3(a0, a1, st1[15]);
    const float b1 = MAX3(a2, a3, pmax);
    pmax = MAX3(b0, b1, a4);
  }
  pmax = fmaxf(pmax, __shfl_xor(pmax, 32));

  // ---- defer-max (T13): rescale is pure per-lane
  if (!__all(pmax - m <= DMTHR)) {
    const float mn = fmaxf(m, pmax);
    const float alpha = EXP2(m - mn);
    m = mn;
    l *= alpha;
#pragma unroll
    for (int r = 0; r < 16; ++r) od0[r] *= alpha;
#pragma unroll
    for (int r = 0; r < 16; ++r) od1[r] *= alpha;
  }

  // ---- P = exp2(S - m); in-lane partial sum
  float ps = 0.f;
#pragma unroll
  for (int r = 0; r < 16; ++r) { const float p = EXP2(st0[r] - m); st0[r] = p; ps += p; }
  if (ctmax)
#pragma unroll
    for (int r = 0; r < 16; ++r) { const float p = EXP2(st1[r] - m); st1[r] = p; ps += p; }
  l += ps;

  // ---- P -> B-frag via cvt_pk + permlane32_swap (T12); O^T += mfma(V^T, P^T)
  __builtin_amdgcn_s_setprio(1);
#define PV_CT(stv, CT)                                                          \
  _Pragma("unroll")                                                             \
  for (int t = 0; t < 2; ++t) {                                                 \
    u32 x0 = pkbits(stv[8 * t + 0], stv[8 * t + 1]);                            \
    u32 x1 = pkbits(stv[8 * t + 2], stv[8 * t + 3]);                            \
    u32 y0 = pkbits(stv[8 * t + 4], stv[8 * t + 5]);                            \
    u32 y1 = pkbits(stv[8 * t + 6], stv[8 * t + 7]);                            \
    plswap(x0, y0); plswap(x1, y1);                                             \
    const f16x8 pf = __builtin_bit_cast(f16x8, (u32x4){x0, x1, y0, y1});        \
    const int kcol = (2 * (CT) + t) * 16 + 8 * hi;                              \
    { const f16x8 vf = *(const f16x8*)&Vb[(q32 << 6) + (swzb(q32) ^ kcol)];     \
      od0 = MFMA32(vf, pf, od0); }                                              \
    { const int row = 32 + q32;                                                 \
      const f16x8 vf = *(const f16x8*)&Vb[(row << 6) + (swzb(row) ^ kcol)];     \
      od1 = MFMA32(vf, pf, od1); }                                              \
  }
  PV_CT(st0, 0);
  if (ctmax) { PV_CT(st1, 1); }
#undef PV_CT
  __builtin_amdgcn_s_setprio(0);
}

// 32x32x16 swapped flash attn. A-frag: row=l&31, k=(l>>5)*8+j. B-frag: col=l&31 (q).
// C/D: col=l&31 (q), row=(reg&3)+8*(reg>>2)+4*(l>>5)  [m74/m101]
// Two 64-k tiles per barrier (4 LDS buffers).
// waves_per_eu(4) -> VGPR cap 128 (launch_bounds(512,4) empirically capped at 64 -> spills)
__global__ __launch_bounds__(512) __attribute__((amdgpu_waves_per_eu(4)))
void attn_fwd(const float* __restrict__ qp, const float* __restrict__ kp,
              const float* __restrict__ vp, float* __restrict__ op) {
  __shared__ _Float16 Kl[4][KVB * 64];  // Kl[buf][k][d], swizzled rows
  __shared__ _Float16 Vt[4][64 * KVB];  // Vt[buf][d][k], swizzled rows

  const int bh = blockIdx.x;
  constexpr int g8[8] = {7, 6, 5, 4, 0, 1, 2, 3};  // CU pairs (y, y+4) sum NT=36
  const int qt = g8[blockIdx.y];

  const int tid = threadIdx.x;
  const int wid = tid >> 6;
  const int lane = tid & 63;
  const int q32 = lane & 31;
  const int hi = lane >> 5;

  const size_t base = (size_t)bh * (S * D);
  const int Rp = qt * QTILE + wid * 32;  // wave's first q row

  // ---- Q B-frags: bq[t][j] = Q[Rp+q32][16t + 8hi + j] * QSCALE
  f16x8 bq[4];
  {
    const float* qg = qp + base + (size_t)(Rp + q32) * D + 8 * hi;
#pragma unroll
    for (int t = 0; t < 4; ++t) {
      f32x4 a = *(const f32x4*)(qg + 16 * t);
      f32x4 b = *(const f32x4*)(qg + 16 * t + 4);
#pragma unroll
      for (int j = 0; j < 4; ++j) bq[t][j] = (_Float16)(a[j] * QSCALE);
#pragma unroll
      for (int j = 0; j < 4; ++j) bq[t][4 + j] = (_Float16)(b[j] * QSCALE);
    }
  }

  f32x16 od0 = {}, od1 = {};      // O^T: d = 32*dt + 8*(r>>2) + 4*hi + (r&3), q = q32
  float m = -INFINITY, l = 0.f;   // per-lane, own q row

  const int NT = 4 * qt + 4;      // tiles (always even)

  // ---- staging geometry: row-pair rp, 4-col group cg (per 64x64 tile)
  const int rp = tid >> 4;        // 0..31
  const int cg = tid & 15;
  const int r0 = 2 * rp, r1 = 2 * rp + 1;
  const int c4 = cg * 4;
  const int kw0 = (r0 << 6) + (swzb(r0) ^ c4);
  const int kw1 = (r1 << 6) + (swzb(r1) ^ c4);
  const int vw0 = ((c4 + 0) << 6) + (swzb(c4 + 0) ^ r0);
  const int vw1 = ((c4 + 1) << 6) + (swzb(c4 + 1) ^ r0);
  const int vw2 = ((c4 + 2) << 6) + (swzb(c4 + 2) ^ r0);
  const int vw3 = ((c4 + 3) << 6) + (swzb(c4 + 3) ^ r0);

#define LOADT(kt, K0, K1, V0, V1)                                        \
  do {                                                                   \
    const float* kg_ = kp + base + (size_t)((kt) * KVB + r0) * D + c4;   \
    const float* vg_ = vp + base + (size_t)((kt) * KVB + r0) * D + c4;   \
    K0 = *(const f32x4*)kg_; K1 = *(const f32x4*)(kg_ + D);              \
    V0 = *(const f32x4*)vg_; V1 = *(const f32x4*)(vg_ + D);              \
  } while (0)

#define WRITET(buf, K0, K1, V0, V1)                                      \
  do {                                                                   \
    f16x4 k0h_, k1h_;                                                    \
    _Pragma("unroll")                                                    \
    for (int j = 0; j < 4; ++j) {                                        \
      k0h_[j] = (_Float16)K0[j]; k1h_[j] = (_Float16)K1[j];              \
    }                                                                    \
    *(f16x4*)&Kl[buf][kw0] = k0h_;                                       \
    *(f16x4*)&Kl[buf][kw1] = k1h_;                                       \
    *(u32*)&Vt[buf][vw0] = pkbits(V0[0], V1[0]);                         \
    *(u32*)&Vt[buf][vw1] = pkbits(V0[1], V1[1]);                         \
    *(u32*)&Vt[buf][vw2] = pkbits(V0[2], V1[2]);                         \
    *(u32*)&Vt[buf][vw3] = pkbits(V0[3], V1[3]);                         \
  } while (0)

  // ---- main loop: two tiles per barrier
  f32x4 ka0, ka1, va0, va1, kb0, kb1, vb0, vb1;
  LOADT(0, ka0, ka1, va0, va1);
  LOADT(1, kb0, kb1, vb0, vb1);

  for (int ktp = 0; ktp < NT; ktp += 2) {
    const int b0 = ktp & 2;  // buffer pair alternates {0,1} / {2,3}
    WRITET(b0, ka0, ka1, va0, va1);
    WRITET(b0 + 1, kb0, kb1, vb0, vb1);
    if (ktp + 2 < NT) LOADT(ktp + 2, ka0, ka1, va0, va1);  // >1 compute phase of cover
    __syncthreads();  // pair ready; prior pair's reads are barrier-ordered
    compute_tile(ktp, Rp, q32, hi, Kl[b0], Vt[b0], bq, od0, od1, m, l);
    if (ktp + 3 < NT) LOADT(ktp + 3, kb0, kb1, vb0, vb1);  // lands under next compute
    compute_tile(ktp + 1, Rp, q32, hi, Kl[b0 + 1], Vt[b0 + 1], bq, od0, od1, m, l);
  }
#undef LOADT
#undef WRITET

  // ---- epilogue: l across partner, scale, b128 stores
  const float lt = l + __shfl_xor(l, 32);
  const float inv = 1.f / lt;
  float* og = op + base + (size_t)(Rp + q32) * D + 4 * hi;
#pragma unroll
  for (int gq = 0; gq < 4; ++gq) {
    f32x4 w0, w1;
#pragma unroll
    for (int i = 0; i < 4; ++i) w0[i] = od0[4 * gq + i] * inv;
#pragma unroll
    for (int i = 0; i < 4; ++i) w1[i] = od1[4 * gq + i] * inv;
    *(f32x4*)(og + 8 * gq) = w0;
    *(f32x4*)(og + 32 + 8 * gq) = w1;
  }
}

extern "C" void kernel_launch(void* const* d_in, const int* in_sizes, int n_in,
                              void* d_out, int out_size, void* d_ws, size_t ws_size,
                              hipStream_t stream) {
  const float* q = (const float*)d_in[0];
  const float* k = (const float*)d_in[1];
  const float* v = (const float*)d_in[2];
  float* out = (float*)d_out;
  dim3 grid(BH, NQT);
  attn_fwd<<<grid, 512, 0, stream>>>(q, k, v, out);
}

// Round 11
// 69.826 us; speedup vs baseline: 2.0665x; 2.0543x over previous
//
#include <hip/hip_runtime.h>
#include <math.h>

constexpr int S = 2048, D = 64;
constexpr int BH = 64;
constexpr int QTILE = 256;      // 8 waves x 32 q rows
constexpr int KVB = 64;
constexpr int NQT = S / QTILE;  // 8
constexpr float QSCALE = 0.18033688011112042f;  // log2(e)/8
constexpr float DMTHR = 5.0f;   // defer-max threshold (exp2 domain)

typedef float f32x4 __attribute__((ext_vector_type(4)));
typedef float f32x16 __attribute__((ext_vector_type(16)));
typedef _Float16 f16x8 __attribute__((ext_vector_type(8)));
typedef _Float16 f16x4 __attribute__((ext_vector_type(4)));
typedef unsigned int u32;
typedef unsigned int u32x4 __attribute__((ext_vector_type(4)));

#define MFMA32(a, b, c) __builtin_amdgcn_mfma_f32_32x32x16_f16((a), (b), (c), 0, 0, 0)

#if __has_builtin(__builtin_amdgcn_exp2f)
#define EXP2(x) __builtin_amdgcn_exp2f(x)
#else
#define EXP2(x) exp2f(x)
#endif

#define MAX3(a, b, c) fmaxf(fmaxf((a), (b)), (c))  // fuses to v_max3_f32

__device__ __forceinline__ u32 pkbits(float a, float b) {
  return __builtin_bit_cast(u32, __builtin_amdgcn_cvt_pkrtz(a, b));
}
// exchanges a.lanes[32:63] with b.lanes[0:31]; a,b must be distinct values
__device__ __forceinline__ void plswap(u32& a, u32& b) {
  asm volatile("v_permlane32_swap_b32 %0, %1" : "+v"(a), "+v"(b));
}
// XOR swizzle (units of 8 halves): bank period 64 rows
__device__ __forceinline__ int swzb(int row) { return ((row & 7) ^ (row >> 3)) << 3; }

// ---- per-tile compute, forced inline
__device__ __forceinline__ void compute_tile(
    const int kt, const int Rp, const int q32, const int hi,
    const _Float16* __restrict__ Kb, const _Float16* __restrict__ Vb,
    const f16x8 (&bq)[4], f32x16& od0, f32x16& od1, float& m, float& l) {
  const int ck = kt * KVB;
  if (ck > Rp + 31) return;         // wave fully masked
  const int rel = Rp - ck;          // >= 0, multiple of 32
  const int ctmax = (rel >= 32) ? 1 : 0;
  const bool needmask = (32 * ctmax + 31 > rel);

  // ---- S^T = mfma(K, Q): lane owns q=Rp+q32, k = 32ct + 8*(r>>2)+4hi+(r&3)
  f32x16 st0 = {}, st1 = {};
  __builtin_amdgcn_s_setprio(1);
#pragma unroll
  for (int t = 0; t < 4; ++t) {
    f16x8 a = *(const f16x8*)&Kb[(q32 << 6) + (swzb(q32) ^ (16 * t + 8 * hi))];
    st0 = MFMA32(a, bq[t], st0);
  }
  if (ctmax) {
    const int row = 32 + q32;
#pragma unroll
    for (int t = 0; t < 4; ++t) {
      f16x8 a = *(const f16x8*)&Kb[(row << 6) + (swzb(row) ^ (16 * t + 8 * hi))];
      st1 = MFMA32(a, bq[t], st1);
    }
  }
  __builtin_amdgcn_s_setprio(0);

  if (needmask) {  // one diagonal tile per wave over whole kernel
    const int qrel = rel + q32;
#pragma unroll
    for (int gq = 0; gq < 4; ++gq)
#pragma unroll
      for (int i = 0; i < 4; ++i) {
        if (8 * gq + 4 * hi + i > qrel) st0[4 * gq + i] = -INFINITY;
        if (ctmax && (32 + 8 * gq + 4 * hi + i > qrel)) st1[4 * gq + i] = -INFINITY;
      }
  }

  // ---- row max: v_max3 tree (depth ~4) + cross-half shuffle
  float pmax;
  {
    const float a0 = MAX3(st0[0], st0[1], st0[2]);
    const float a1 = MAX3(st0[3], st0[4], st0[5]);
    const float a2 = MAX3(st0[6], st0[7], st0[8]);
    const float a3 = MAX3(st0[9], st0[10], st0[11]);
    const float a4 = MAX3(st0[12], st0[13], st0[14]);
    const float b0 = MAX3(a0, a1, st0[15]);
    const float b1 = fmaxf(a2, a3);
    pmax = MAX3(b0, b1, a4);
  }
  if (ctmax) {
    const float a0 = MAX3(st1[0], st1[1], st1[2]);
    const float a1 = MAX3(st1[3], st1[4], st1[5]);
    const float a2 = MAX3(st1[6], st1[7], st1[8]);
    const float a3 = MAX3(st1[9], st1[10], st1[11]);
    const float a4 = MAX3(st1[12], st1[13], st1[14]);
    const float b0 = MAX3(a0, a1, st1[15]);
    const float b1 = MAX3(a2, a3, pmax);
    pmax = MAX3(b0, b1, a4);
  }
  pmax = fmaxf(pmax, __shfl_xor(pmax, 32));

  // ---- defer-max (T13): rescale is pure per-lane
  if (!__all(pmax - m <= DMTHR)) {
    const float mn = fmaxf(m, pmax);
    const float alpha = EXP2(m - mn);
    m = mn;
    l *= alpha;
#pragma unroll
    for (int r = 0; r < 16; ++r) od0[r] *= alpha;
#pragma unroll
    for (int r = 0; r < 16; ++r) od1[r] *= alpha;
  }

  // ---- P = exp2(S - m); in-lane partial sum
  float ps = 0.f;
#pragma unroll
  for (int r = 0; r < 16; ++r) { const float p = EXP2(st0[r] - m); st0[r] = p; ps += p; }
  if (ctmax)
#pragma unroll
    for (int r = 0; r < 16; ++r) { const float p = EXP2(st1[r] - m); st1[r] = p; ps += p; }
  l += ps;

  // ---- P -> B-frag via cvt_pk + permlane32_swap (T12); O^T += mfma(V^T, P^T)
  __builtin_amdgcn_s_setprio(1);
#define PV_CT(stv, CT)                                                          \
  _Pragma("unroll")                                                             \
  for (int t = 0; t < 2; ++t) {                                                 \
    u32 x0 = pkbits(stv[8 * t + 0], stv[8 * t + 1]);                            \
    u32 x1 = pkbits(stv[8 * t + 2], stv[8 * t + 3]);                            \
    u32 y0 = pkbits(stv[8 * t + 4], stv[8 * t + 5]);                            \
    u32 y1 = pkbits(stv[8 * t + 6], stv[8 * t + 7]);                            \
    plswap(x0, y0); plswap(x1, y1);                                             \
    const f16x8 pf = __builtin_bit_cast(f16x8, (u32x4){x0, x1, y0, y1});        \
    const int kcol = (2 * (CT) + t) * 16 + 8 * hi;                              \
    { const f16x8 vf = *(const f16x8*)&Vb[(q32 << 6) + (swzb(q32) ^ kcol)];     \
      od0 = MFMA32(vf, pf, od0); }                                              \
    { const int row = 32 + q32;                                                 \
      const f16x8 vf = *(const f16x8*)&Vb[(row << 6) + (swzb(row) ^ kcol)];     \
      od1 = MFMA32(vf, pf, od1); }                                              \
  }
  PV_CT(st0, 0);
  if (ctmax) { PV_CT(st1, 1); }
#undef PV_CT
  __builtin_amdgcn_s_setprio(0);
}

// 32x32x16 swapped flash attn. A-frag: row=l&31, k=(l>>5)*8+j. B-frag: col=l&31 (q).
// C/D: col=l&31 (q), row=(reg&3)+8*(reg>>2)+4*(l>>5)  [m74/m101]
// Two 64-k tiles per barrier (4 LDS buffers).
// launch_bounds(512,2): min 2 waves/EU -> 256-reg budget/wave -> demand ~140 fits,
// no spills ((512,4)'s 128 budget forced ~31MB/dispatch of scratch traffic, R8-R10).
__global__ __launch_bounds__(512, 2)
void attn_fwd(const float* __restrict__ qp, const float* __restrict__ kp,
              const float* __restrict__ vp, float* __restrict__ op) {
  __shared__ _Float16 Kl[4][KVB * 64];  // Kl[buf][k][d], swizzled rows
  __shared__ _Float16 Vt[4][64 * KVB];  // Vt[buf][d][k], swizzled rows

  const int bh = blockIdx.x;
  constexpr int g8[8] = {7, 6, 5, 4, 0, 1, 2, 3};  // CU pairs (y, y+4) sum NT=36
  const int qt = g8[blockIdx.y];

  const int tid = threadIdx.x;
  const int wid = tid >> 6;
  const int lane = tid & 63;
  const int q32 = lane & 31;
  const int hi = lane >> 5;

  const size_t base = (size_t)bh * (S * D);
  const int Rp = qt * QTILE + wid * 32;  // wave's first q row

  // ---- Q B-frags: bq[t][j] = Q[Rp+q32][16t + 8hi + j] * QSCALE
  f16x8 bq[4];
  {
    const float* qg = qp + base + (size_t)(Rp + q32) * D + 8 * hi;
#pragma unroll
    for (int t = 0; t < 4; ++t) {
      f32x4 a = *(const f32x4*)(qg + 16 * t);
      f32x4 b = *(const f32x4*)(qg + 16 * t + 4);
#pragma unroll
      for (int j = 0; j < 4; ++j) bq[t][j] = (_Float16)(a[j] * QSCALE);
#pragma unroll
      for (int j = 0; j < 4; ++j) bq[t][4 + j] = (_Float16)(b[j] * QSCALE);
    }
  }

  f32x16 od0 = {}, od1 = {};      // O^T: d = 32*dt + 8*(r>>2) + 4*hi + (r&3), q = q32
  float m = -INFINITY, l = 0.f;   // per-lane, own q row

  const int NT = 4 * qt + 4;      // tiles (always even)

  // ---- staging geometry: row-pair rp, 4-col group cg (per 64x64 tile)
  const int rp = tid >> 4;        // 0..31
  const int cg = tid & 15;
  const int r0 = 2 * rp, r1 = 2 * rp + 1;
  const int c4 = cg * 4;
  const int kw0 = (r0 << 6) + (swzb(r0) ^ c4);
  const int kw1 = (r1 << 6) + (swzb(r1) ^ c4);
  const int vw0 = ((c4 + 0) << 6) + (swzb(c4 + 0) ^ r0);
  const int vw1 = ((c4 + 1) << 6) + (swzb(c4 + 1) ^ r0);
  const int vw2 = ((c4 + 2) << 6) + (swzb(c4 + 2) ^ r0);
  const int vw3 = ((c4 + 3) << 6) + (swzb(c4 + 3) ^ r0);

#define LOADT(kt, K0, K1, V0, V1)                                        \
  do {                                                                   \
    const float* kg_ = kp + base + (size_t)((kt) * KVB + r0) * D + c4;   \
    const float* vg_ = vp + base + (size_t)((kt) * KVB + r0) * D + c4;   \
    K0 = *(const f32x4*)kg_; K1 = *(const f32x4*)(kg_ + D);              \
    V0 = *(const f32x4*)vg_; V1 = *(const f32x4*)(vg_ + D);              \
  } while (0)

#define WRITET(buf, K0, K1, V0, V1)                                      \
  do {                                                                   \
    f16x4 k0h_, k1h_;                                                    \
    _Pragma("unroll")                                                    \
    for (int j = 0; j < 4; ++j) {                                        \
      k0h_[j] = (_Float16)K0[j]; k1h_[j] = (_Float16)K1[j];              \
    }                                                                    \
    *(f16x4*)&Kl[buf][kw0] = k0h_;                                       \
    *(f16x4*)&Kl[buf][kw1] = k1h_;                                       \
    *(u32*)&Vt[buf][vw0] = pkbits(V0[0], V1[0]);                         \
    *(u32*)&Vt[buf][vw1] = pkbits(V0[1], V1[1]);                         \
    *(u32*)&Vt[buf][vw2] = pkbits(V0[2], V1[2]);                         \
    *(u32*)&Vt[buf][vw3] = pkbits(V0[3], V1[3]);                         \
  } while (0)

  // ---- main loop: two tiles per barrier
  f32x4 ka0, ka1, va0, va1, kb0, kb1, vb0, vb1;
  LOADT(0, ka0, ka1, va0, va1);
  LOADT(1, kb0, kb1, vb0, vb1);

  for (int ktp = 0; ktp < NT; ktp += 2) {
    const int b0 = ktp & 2;  // buffer pair alternates {0,1} / {2,3}
    WRITET(b0, ka0, ka1, va0, va1);
    WRITET(b0 + 1, kb0, kb1, vb0, vb1);
    if (ktp + 2 < NT) LOADT(ktp + 2, ka0, ka1, va0, va1);  // >1 compute phase of cover
    __syncthreads();  // pair ready; prior pair's reads are barrier-ordered
    compute_tile(ktp, Rp, q32, hi, Kl[b0], Vt[b0], bq, od0, od1, m, l);
    if (ktp + 3 < NT) LOADT(ktp + 3, kb0, kb1, vb0, vb1);  // lands under next compute
    compute_tile(ktp + 1, Rp, q32, hi, Kl[b0 + 1], Vt[b0 + 1], bq, od0, od1, m, l);
  }
#undef LOADT
#undef WRITET

  // ---- epilogue: l across partner, scale, b128 stores
  const float lt = l + __shfl_xor(l, 32);
  const float inv = 1.f / lt;
  float* og = op + base + (size_t)(Rp + q32) * D + 4 * hi;
#pragma unroll
  for (int gq = 0; gq < 4; ++gq) {
    f32x4 w0, w1;
#pragma unroll
    for (int i = 0; i < 4; ++i) w0[i] = od0[4 * gq + i] * inv;
#pragma unroll
    for (int i = 0; i < 4; ++i) w1[i] = od1[4 * gq + i] * inv;
    *(f32x4*)(og + 8 * gq) = w0;
    *(f32x4*)(og + 32 + 8 * gq) = w1;
  }
}

extern "C" void kernel_launch(void* const* d_in, const int* in_sizes, int n_in,
                              void* d_out, int out_size, void* d_ws, size_t ws_size,
                              hipStream_t stream) {
  const float* q = (const float*)d_in[0];
  const float* k = (const float*)d_in[1];
  const float* v = (const float*)d_in[2];
  float* out = (float*)d_out;
  dim3 grid(BH, NQT);
  attn_fwd<<<grid, 512, 0, stream>>>(q, k, v, out);
}